// Round 2
// baseline (823.958 us; speedup 1.0000x reference)
//
#include <hip/hip_runtime.h>
#include <hip/hip_bf16.h>

// ChildSumTreeLSTM, fp32 in/out (reference dtypes), depth=17, N=2^18-1, D_IN=H=128.
// Compute: split-bf16 MFMA (a = a_hi + a_lo, 3 MFMAs, drop lo*lo) ~= fp32 accuracy.
//  k_prep : split 8 weight matrices into hi/lo bf16, pre-swizzled to B-fragment order
//  k_leaf : fused x@[Wi|Wo|Wu]+b -> activations -> h,c (fp32)
//  k_level: fused x@W(4 gates) + ht@[Ui|Uo|Uu] + hc@Uf + cell update (x-GEMM merged
//           into the same accumulators as U-GEMM; no X intermediate buffer)
//  k_out  : root (h,c) -> d_out (256 floats)
// Workspace: 512KB swizzled weights + 4 * NL*128 fp32 (h0,h1,c0,c1) = 256.5 MiB.

typedef __bf16 bf16_t;
typedef __bf16 bf16x8 __attribute__((ext_vector_type(8)));
typedef float  f32x4  __attribute__((ext_vector_type(4)));

#define MFMA16(a, b, c) __builtin_amdgcn_mfma_f32_16x16x32_bf16((a), (b), (c), 0, 0, 0)

__device__ __forceinline__ float sigm(float x) { return 1.0f / (1.0f + __expf(-x)); }
__device__ __forceinline__ float tanh_(float x) {
    float a = fabsf(x);
    float e = __expf(2.0f * a);           // -> +inf for large a => t = 1
    float t = 1.0f - 2.0f / (e + 1.0f);
    return copysignf(t, x);
}

// ---------------------------------------------------------------------------
// Swizzled weight layout per 128x128 matrix (slot s at SW + s*32768):
//   hi[idx], lo = hi + 16384,  idx = ((nt*4 + kb)*64 + lane)*8 + j
//   element = W[kb*32 + (lane>>4)*8 + j][nt*16 + (lane&15)]
// Slots: 0=Wi 1=Wf 2=Wo 3=Wu 4=Ui 5=Uf 6=Uo 7=Uu
__global__ __launch_bounds__(256)
void k_prep(const float* __restrict__ Wi, const float* __restrict__ Wf,
            const float* __restrict__ Wo, const float* __restrict__ Wu,
            const float* __restrict__ Ui, const float* __restrict__ Uf,
            const float* __restrict__ Uo, const float* __restrict__ Uu,
            bf16_t* __restrict__ SW)
{
    const float* src;
    switch (blockIdx.x) {
        case 0: src = Wi; break; case 1: src = Wf; break;
        case 2: src = Wo; break; case 3: src = Wu; break;
        case 4: src = Ui; break; case 5: src = Uf; break;
        case 6: src = Uo; break; default: src = Uu; break;
    }
    bf16_t* hi = SW + (size_t)blockIdx.x * 32768;
    bf16_t* lo = hi + 16384;
    for (int idx = threadIdx.x; idx < 16384; idx += 256) {
        int j = idx & 7, lane = (idx >> 3) & 63, kb = (idx >> 9) & 3, nt = idx >> 11;
        int k = kb * 32 + (lane >> 4) * 8 + j;
        int n = nt * 16 + (lane & 15);
        float w = src[k * 128 + n];
        bf16_t hh = (bf16_t)w;
        hi[idx] = hh;
        lo[idx] = (bf16_t)(w - (float)hh);
    }
}

// stage 16 consecutive floats -> hi/lo bf16 planes (16B-aligned dests)
__device__ __forceinline__ void split16(const float* __restrict__ src,
                                        bf16_t* __restrict__ dhi,
                                        bf16_t* __restrict__ dlo)
{
    float tmp[16];
    *(float4*)&tmp[0]  = ((const float4*)src)[0];
    *(float4*)&tmp[4]  = ((const float4*)src)[1];
    *(float4*)&tmp[8]  = ((const float4*)src)[2];
    *(float4*)&tmp[12] = ((const float4*)src)[3];
    bf16_t hb[16], lb[16];
#pragma unroll
    for (int j = 0; j < 16; j++) {
        float f = tmp[j];
        bf16_t hh = (bf16_t)f;
        hb[j] = hh;
        lb[j] = (bf16_t)(f - (float)hh);
    }
    *(bf16x8*)&dhi[0] = *(bf16x8*)&hb[0];
    *(bf16x8*)&dhi[8] = *(bf16x8*)&hb[8];
    *(bf16x8*)&dlo[0] = *(bf16x8*)&lb[0];
    *(bf16x8*)&dlo[8] = *(bf16x8*)&lb[8];
}

// ---------------------------------------------------------------------------
// Leaves: 32 leaves/block. acc = x@[Wi|Wo|Wu] (split-3), then i,o,u -> h,c.
__global__ __launch_bounds__(256)
void k_leaf(const float* __restrict__ x, int leaf_off,
            const bf16_t* __restrict__ SW,
            const float* __restrict__ bi, const float* __restrict__ bo,
            const float* __restrict__ bu,
            float* __restrict__ h_out, float* __restrict__ c_out)
{
    __shared__ __align__(16) bf16_t AHi[32][136];
    __shared__ __align__(16) bf16_t ALo[32][136];
    __shared__ __align__(16) float  Ch[32][196];   // one j-half: [i|o|u] x 64 (+4 pad)

    const int tid = threadIdx.x;
    const int n0  = blockIdx.x * 32;

    {   // stage x rows (fp32 -> hi/lo bf16)
        int r = tid >> 3, cb = (tid & 7) * 16;
        split16(x + (size_t)(leaf_off + n0 + r) * 128 + cb, &AHi[r][cb], &ALo[r][cb]);
    }
    __syncthreads();

    const int wave = tid >> 6, lane = tid & 63;
    const int quad = lane >> 4, lc = lane & 15;

    f32x4 acc[6][2];
#pragma unroll
    for (int nt = 0; nt < 6; nt++)
#pragma unroll
        for (int mt = 0; mt < 2; mt++) acc[nt][mt] = (f32x4){0.f, 0.f, 0.f, 0.f};

    for (int kb = 0; kb < 4; kb++) {
        const int k0 = kb * 32 + quad * 8;
        bf16x8 xh0 = *(const bf16x8*)&AHi[lc][k0];
        bf16x8 xl0 = *(const bf16x8*)&ALo[lc][k0];
        bf16x8 xh1 = *(const bf16x8*)&AHi[16 + lc][k0];
        bf16x8 xl1 = *(const bf16x8*)&ALo[16 + lc][k0];
#pragma unroll
        for (int nt = 0; nt < 6; nt++) {
            int col_base = wave * 96 + nt * 16;
            int g = col_base >> 7;                      // 0=i,1=o,2=u
            int slot = (g == 0) ? 0 : (g == 1) ? 2 : 3; // Wi,Wo,Wu
            const bf16_t* Bh = SW + (size_t)slot * 32768 +
                               ((size_t)(((col_base & 127) >> 4) * 4 + kb) * 64 + lane) * 8;
            const bf16_t* Bl = Bh + 16384;
            bf16x8 bh = *(const bf16x8*)Bh;
            bf16x8 bl = *(const bf16x8*)Bl;
            f32x4 a0 = acc[nt][0];
            a0 = MFMA16(xh0, bh, a0); a0 = MFMA16(xh0, bl, a0); a0 = MFMA16(xl0, bh, a0);
            acc[nt][0] = a0;
            f32x4 a1 = acc[nt][1];
            a1 = MFMA16(xh1, bh, a1); a1 = MFMA16(xh1, bl, a1); a1 = MFMA16(xl1, bh, a1);
            acc[nt][1] = a1;
        }
    }

    for (int p = 0; p < 2; p++) {
        __syncthreads();
        // dump this j-half
#pragma unroll
        for (int nt = 0; nt < 6; nt++) {
            int col_base = wave * 96 + nt * 16;
            if (((col_base >> 6) & 1) == p) {
                int dst = (col_base >> 7) * 64 + (col_base & 63);
#pragma unroll
                for (int mt = 0; mt < 2; mt++)
#pragma unroll
                    for (int r = 0; r < 4; r++)
                        Ch[mt * 16 + quad * 4 + r][dst + lc] = acc[nt][mt][r];
            }
        }
        __syncthreads();
        for (int idx = tid; idx < 32 * 64; idx += 256) {
            int m = idx >> 6, jj = idx & 63, j = p * 64 + jj;
            float iv = sigm(Ch[m][jj] + bi[j]);
            float ov = sigm(Ch[m][64 + jj] + bo[j]);
            float uv = tanh_(Ch[m][128 + jj] + bu[j]);
            float cv = iv * uv;
            float hv = ov * tanh_(cv);
            size_t node = (size_t)(n0 + m);
            h_out[node * 128 + j] = hv;
            c_out[node * 128 + j] = cv;
        }
    }
}

// ---------------------------------------------------------------------------
// One tree level: 32 parents/block. Wave gates: w0=i w1=f w2=o w3=u.
// accM[nt][mt] = x@W_g (all waves) + ht@U_g (waves i,o,u). accF = hc@Uf (cols 2w,2w+1).
__global__ __launch_bounds__(256)
void k_level(const float* __restrict__ x, const bf16_t* __restrict__ SW,
             const float* __restrict__ bi, const float* __restrict__ bf_,
             const float* __restrict__ bo, const float* __restrict__ bu,
             const float* __restrict__ h_in, const float* __restrict__ c_in,
             float* __restrict__ h_out, float* __restrict__ c_out,
             int sl, int nl)
{
    // staging region (phase 1) aliased with dump region (phase 2)
    __shared__ __align__(16) char smem[52224];
    bf16_t (*XHi)[136]  = (bf16_t(*)[136])(smem);           //  8704 B
    bf16_t (*XLo)[136]  = (bf16_t(*)[136])(smem + 8704);    //  8704 B
    bf16_t (*HChi)[136] = (bf16_t(*)[136])(smem + 17408);   // 17408 B
    bf16_t (*HClo)[136] = (bf16_t(*)[136])(smem + 34816);   // 17408 B
    float  (*C1h)[196]  = (float(*)[196])(smem);            // 25088 B  [i|o|u]x64
    float  (*XFh)[68]   = (float(*)[68])(smem + 25088);     //  8704 B
    float  (*C2h)[68]   = (float(*)[68])(smem + 33792);     // 17408 B

    const int tid = threadIdx.x;
    const int n0  = blockIdx.x * 32;

    {   // stage x rows of the 32 parents
        int r = tid >> 3, cb = (tid & 7) * 16;
        split16(x + (size_t)(sl + n0 + r) * 128 + cb, &XHi[r][cb], &XLo[r][cb]);
    }
    // stage 64 children h rows (fp32 -> hi/lo), zero-fill beyond level
    for (int i = tid; i < 64 * 8; i += 256) {
        int r = i >> 3, cb = (i & 7) * 16;
        int row = 2 * n0 + r;
        if (row < 2 * nl) {
            split16(h_in + (size_t)row * 128 + cb, &HChi[r][cb], &HClo[r][cb]);
        } else {
            bf16x8 z = (bf16x8)(bf16_t)0.f;
            *(bf16x8*)&HChi[r][cb] = z; *(bf16x8*)&HChi[r][cb + 8] = z;
            *(bf16x8*)&HClo[r][cb] = z; *(bf16x8*)&HClo[r][cb + 8] = z;
        }
    }
    __syncthreads();

    const int wave = tid >> 6, lane = tid & 63;
    const int quad = lane >> 4, lc = lane & 15;

    const bf16_t* Whi = SW + (size_t)wave * 32768;
    const bf16_t* Wlo = Whi + 16384;
    const bf16_t* Uhi = nullptr, *Ulo = nullptr;
    if (wave != 1) {
        int us = (wave == 0) ? 4 : (wave == 2) ? 6 : 7;   // Ui,Uo,Uu
        Uhi = SW + (size_t)us * 32768; Ulo = Uhi + 16384;
    }
    const bf16_t* Fhi = SW + (size_t)5 * 32768;           // Uf
    const bf16_t* Flo = Fhi + 16384;

    f32x4 accM[8][2];
    f32x4 accF[2][4];
#pragma unroll
    for (int nt = 0; nt < 8; nt++)
#pragma unroll
        for (int mt = 0; mt < 2; mt++) accM[nt][mt] = (f32x4){0.f, 0.f, 0.f, 0.f};
#pragma unroll
    for (int t = 0; t < 2; t++)
#pragma unroll
        for (int mt = 0; mt < 4; mt++) accF[t][mt] = (f32x4){0.f, 0.f, 0.f, 0.f};

    for (int kb = 0; kb < 4; kb++) {
        const int k0 = kb * 32 + quad * 8;
        bf16x8 xh[2], xl[2];
        xh[0] = *(const bf16x8*)&XHi[lc][k0];      xl[0] = *(const bf16x8*)&XLo[lc][k0];
        xh[1] = *(const bf16x8*)&XHi[16 + lc][k0]; xl[1] = *(const bf16x8*)&XLo[16 + lc][k0];

        bf16x8 th[2], tl[2];
        if (wave != 1) {   // child-sum A-fragments built on the fly (no HT plane)
#pragma unroll
            for (int mt = 0; mt < 2; mt++) {
                int p2 = (mt * 16 + lc) * 2;
                bf16x8 h0a = *(const bf16x8*)&HChi[p2][k0];
                bf16x8 l0a = *(const bf16x8*)&HClo[p2][k0];
                bf16x8 h1a = *(const bf16x8*)&HChi[p2 + 1][k0];
                bf16x8 l1a = *(const bf16x8*)&HClo[p2 + 1][k0];
#pragma unroll
                for (int j = 0; j < 8; j++) {
                    float s = (float)h0a[j] + (float)l0a[j] + (float)h1a[j] + (float)l1a[j];
                    bf16_t hh = (bf16_t)s;
                    th[mt][j] = hh;
                    tl[mt][j] = (bf16_t)(s - (float)hh);
                }
            }
        }
#pragma unroll
        for (int nt = 0; nt < 8; nt++) {
            const size_t boff = ((size_t)(nt * 4 + kb) * 64 + lane) * 8;
            bf16x8 bWh = *(const bf16x8*)(Whi + boff);
            bf16x8 bWl = *(const bf16x8*)(Wlo + boff);
#pragma unroll
            for (int mt = 0; mt < 2; mt++) {
                f32x4 a = accM[nt][mt];
                a = MFMA16(xh[mt], bWh, a);
                a = MFMA16(xh[mt], bWl, a);
                a = MFMA16(xl[mt], bWh, a);
                accM[nt][mt] = a;
            }
            if (wave != 1) {
                bf16x8 bUh = *(const bf16x8*)(Uhi + boff);
                bf16x8 bUl = *(const bf16x8*)(Ulo + boff);
#pragma unroll
                for (int mt = 0; mt < 2; mt++) {
                    f32x4 a = accM[nt][mt];
                    a = MFMA16(th[mt], bUh, a);
                    a = MFMA16(th[mt], bUl, a);
                    a = MFMA16(tl[mt], bUh, a);
                    accM[nt][mt] = a;
                }
            }
        }
        // GEMM2: f-gate per child, this wave's columns {2w, 2w+1}
        bf16x8 g2h[4], g2l[4];
#pragma unroll
        for (int mt = 0; mt < 4; mt++) {
            g2h[mt] = *(const bf16x8*)&HChi[mt * 16 + lc][k0];
            g2l[mt] = *(const bf16x8*)&HClo[mt * 16 + lc][k0];
        }
#pragma unroll
        for (int t = 0; t < 2; t++) {
            const size_t boff = ((size_t)((2 * wave + t) * 4 + kb) * 64 + lane) * 8;
            bf16x8 bFh = *(const bf16x8*)(Fhi + boff);
            bf16x8 bFl = *(const bf16x8*)(Flo + boff);
#pragma unroll
            for (int mt = 0; mt < 4; mt++) {
                f32x4 a = accF[t][mt];
                a = MFMA16(g2h[mt], bFh, a);
                a = MFMA16(g2h[mt], bFl, a);
                a = MFMA16(g2l[mt], bFh, a);
                accF[t][mt] = a;
            }
        }
    }

    for (int p = 0; p < 2; p++) {
        __syncthreads();    // p0: all LDS reads done (dump aliases staging); p1: epi0 done
        if (wave != 1) {
            int gi = (wave == 0) ? 0 : (wave == 2) ? 1 : 2;
#pragma unroll
            for (int nt4 = 0; nt4 < 4; nt4++) {
                int nt = p * 4 + nt4;
#pragma unroll
                for (int mt = 0; mt < 2; mt++)
#pragma unroll
                    for (int r = 0; r < 4; r++)
                        C1h[mt * 16 + quad * 4 + r][gi * 64 + nt4 * 16 + lc] = accM[nt][mt][r];
            }
        } else {
#pragma unroll
            for (int nt4 = 0; nt4 < 4; nt4++) {
                int nt = p * 4 + nt4;
#pragma unroll
                for (int mt = 0; mt < 2; mt++)
#pragma unroll
                    for (int r = 0; r < 4; r++)
                        XFh[mt * 16 + quad * 4 + r][nt4 * 16 + lc] = accM[nt][mt][r];
            }
        }
        if ((wave >> 1) == p) {     // waves 0,1 dump f-cols 0-63; waves 2,3 cols 64-127
            int cb0 = (2 * wave - 4 * p) * 16;
#pragma unroll
            for (int t = 0; t < 2; t++)
#pragma unroll
                for (int mt = 0; mt < 4; mt++)
#pragma unroll
                    for (int r = 0; r < 4; r++)
                        C2h[mt * 16 + quad * 4 + r][cb0 + t * 16 + lc] = accF[t][mt][r];
        }
        __syncthreads();
        for (int idx = tid; idx < 32 * 64; idx += 256) {
            int m = idx >> 6, jj = idx & 63, j = p * 64 + jj;
            int node = n0 + m;
            if (node < nl) {
                float iv = sigm(C1h[m][jj] + bi[j]);
                float ov = sigm(C1h[m][64 + jj] + bo[j]);
                float uv = tanh_(C1h[m][128 + jj] + bu[j]);
                float xf = XFh[m][jj] + bf_[j];
                float f0 = sigm(xf + C2h[2 * m][jj]);
                float f1 = sigm(xf + C2h[2 * m + 1][jj]);
                float cc0 = c_in[(size_t)(2 * node) * 128 + j];
                float cc1 = c_in[(size_t)(2 * node + 1) * 128 + j];
                float cv = iv * uv + f0 * cc0 + f1 * cc1;
                h_out[(size_t)node * 128 + j] = ov * tanh_(cv);
                c_out[(size_t)node * 128 + j] = cv;
            }
        }
    }
}

__global__ __launch_bounds__(256)
void k_out(const float* __restrict__ h, const float* __restrict__ c,
           float* __restrict__ out)
{
    int t = threadIdx.x;
    if (t < 128)      out[t] = h[t];
    else if (t < 256) out[t] = c[t - 128];
}

// ---------------------------------------------------------------------------
extern "C" void kernel_launch(void* const* d_in, const int* in_sizes, int n_in,
                              void* d_out, int out_size, void* d_ws, size_t ws_size,
                              hipStream_t stream)
{
    const float* x   = (const float*)d_in[0];
    const float* Wi  = (const float*)d_in[1];
    const float* bi  = (const float*)d_in[2];
    const float* Ui  = (const float*)d_in[3];
    const float* Wf  = (const float*)d_in[4];
    const float* bf_ = (const float*)d_in[5];
    const float* Uf  = (const float*)d_in[6];
    const float* Wo  = (const float*)d_in[7];
    const float* bo  = (const float*)d_in[8];
    const float* Uo  = (const float*)d_in[9];
    const float* Wu  = (const float*)d_in[10];
    const float* bu  = (const float*)d_in[11];
    const float* Uu  = (const float*)d_in[12];

    int Nn    = in_sizes[0] / 128;                       // total nodes (2^(d+1)-1)
    int depth = 31 - __builtin_clz((unsigned)(Nn + 1)) - 1;
    int NL    = 1 << depth;                              // leaves
    int Mint  = NL - 1;                                  // internal nodes / leaf offset

    // workspace: 512 KB swizzled weights + 4 * NL*128 fp32 = 256.5 MiB @ depth 17
    bf16_t* SW = (bf16_t*)d_ws;
    float* h0 = (float*)((char*)d_ws + 524288);
    float* h1 = h0 + (size_t)NL * 128;
    float* c0 = h1 + (size_t)NL * 128;
    float* c1 = c0 + (size_t)NL * 128;

    k_prep<<<8, 256, 0, stream>>>(Wi, Wf, Wo, Wu, Ui, Uf, Uo, Uu, SW);
    k_leaf<<<NL / 32, 256, 0, stream>>>(x, Mint, SW, bi, bo, bu, h0, c0);

    const float* hin = h0; const float* cin = c0;
    float* hout = h1;      float* cout = c1;
    for (int l = depth - 1; l >= 0; --l) {
        int nl = 1 << l, sl = nl - 1;
        int blocks = (nl + 31) / 32;
        k_level<<<blocks, 256, 0, stream>>>(x, SW, bi, bf_, bo, bu,
                                            hin, cin, hout, cout, sl, nl);
        const float* th = hin; hin = hout; hout = (float*)th;
        const float* tc = cin; cin = cout; cout = (float*)tc;
    }
    k_out<<<1, 256, 0, stream>>>(hin, cin, (float*)d_out);
}